// Round 4
// baseline (183.455 us; speedup 1.0000x reference)
//
#include <hip/hip_runtime.h>
#include <math.h>

#define NN  8192
#define DIM 128
#define NE  262144
#define XB  128          // xtx partial blocks (64 rows each)
#define HB  128          // histogram / placement chunks
#define EPB (NE / HB)    // 2048 edges per chunk
#define EPT (EPB / 256)  // 8 edges per thread
#define RWB 16           // rows per xw_att block

// ---------------- K1: row norms (blocks [0,2048)) + LDS-private histogram
// (blocks [2048,2048+HB)). Hist saves per-edge local rank -> placement needs
// NO atomics later. partial[h][bin] = per-chunk count.
__global__ __launch_bounds__(256) void k_prep(const float* __restrict__ x,
    const int* __restrict__ ei, float* __restrict__ rinv,
    int* __restrict__ rank, int* __restrict__ partial) {
  __shared__ int ldeg[NN];   // 32 KB
  int bid = blockIdx.x, tid = threadIdx.x;
  if (bid < 2048) {
    int wave = tid >> 6, lane = tid & 63;
    int row  = bid * 4 + wave;
    const float2* x2 = (const float2*)(x + (size_t)row * DIM);
    float2 v = x2[lane];
    float ss = v.x * v.x + v.y * v.y;
    #pragma unroll
    for (int m = 32; m; m >>= 1) ss += __shfl_xor(ss, m);
    if (lane == 0) rinv[row] = 1.0f / sqrtf(ss);
  } else {
    int h = bid - 2048;
    int4* lz = (int4*)ldeg;
    #pragma unroll
    for (int i = tid; i < NN / 4; i += 256) lz[i] = make_int4(0, 0, 0, 0);
    __syncthreads();
    int e0 = h * EPB + tid * EPT;
    int4 c0 = *(const int4*)(ei + NE + e0);      // targets
    int4 c1 = *(const int4*)(ei + NE + e0 + 4);
    int r0 = atomicAdd(&ldeg[c0.x], 1);
    int r1 = atomicAdd(&ldeg[c0.y], 1);
    int r2 = atomicAdd(&ldeg[c0.z], 1);
    int r3 = atomicAdd(&ldeg[c0.w], 1);
    int r4 = atomicAdd(&ldeg[c1.x], 1);
    int r5 = atomicAdd(&ldeg[c1.y], 1);
    int r6 = atomicAdd(&ldeg[c1.z], 1);
    int r7 = atomicAdd(&ldeg[c1.w], 1);
    *(int4*)(rank + e0)     = make_int4(r0, r1, r2, r3);
    *(int4*)(rank + e0 + 4) = make_int4(r4, r5, r6, r7);
    __syncthreads();
    #pragma unroll
    for (int i = tid * 4; i < NN; i += 1024)
      *(int4*)(partial + (size_t)h * NN + i) = *(int4*)&ldeg[i];
  }
}

// ---------------- K2: M = X^T X partials. 128 blocks x 64 rows, staged once.
__global__ __launch_bounds__(256) void k_xtx_partial(const float* __restrict__ x,
    const float* __restrict__ rinv, float* __restrict__ Mpart) {
  __shared__ float xs[64 * DIM];   // 32 KB
  __shared__ float rvs[64];
  int tid = threadIdx.x;
  int row0 = blockIdx.x * 64;
  const float4* xsrc = (const float4*)(x + (size_t)row0 * DIM);
  float4* xdst = (float4*)xs;
  #pragma unroll
  for (int i = 0; i < 8; ++i) xdst[tid + 256 * i] = xsrc[tid + 256 * i];
  if (tid < 64) rvs[tid] = rinv[row0 + tid];
  __syncthreads();

  int ty = tid >> 4, tx = tid & 15;
  float acc[8][8];
  #pragma unroll
  for (int i = 0; i < 8; ++i)
    #pragma unroll
    for (int j = 0; j < 8; ++j) acc[i][j] = 0.f;

  #pragma unroll 2
  for (int r = 0; r < 64; ++r) {
    float4 a0 = *(const float4*)&xs[r * DIM + ty * 8];
    float4 a1 = *(const float4*)&xs[r * DIM + ty * 8 + 4];
    float4 b0 = *(const float4*)&xs[r * DIM + tx * 8];
    float4 b1 = *(const float4*)&xs[r * DIM + tx * 8 + 4];
    float rv = rvs[r];
    float a[8] = {a0.x * rv, a0.y * rv, a0.z * rv, a0.w * rv,
                  a1.x * rv, a1.y * rv, a1.z * rv, a1.w * rv};
    float b[8] = {b0.x, b0.y, b0.z, b0.w, b1.x, b1.y, b1.z, b1.w};
    #pragma unroll
    for (int i = 0; i < 8; ++i)
      #pragma unroll
      for (int j = 0; j < 8; ++j) acc[i][j] += a[i] * b[j];
  }
  float* o = Mpart + (size_t)blockIdx.x * (DIM * DIM);
  #pragma unroll
  for (int i = 0; i < 8; ++i) {
    *(float4*)&o[(ty * 8 + i) * DIM + tx * 8]     = make_float4(acc[i][0], acc[i][1], acc[i][2], acc[i][3]);
    *(float4*)&o[(ty * 8 + i) * DIM + tx * 8 + 4] = make_float4(acc[i][4], acc[i][5], acc[i][6], acc[i][7]);
  }
}

// ---------------- K3: fused Mpart reduce (blocks [0,32)) + per-bin column
// scan of partial (blocks [32,64)) -> chunk prefixes in place, deg, dis.
__global__ __launch_bounds__(256) void k_mid(const float* __restrict__ Mpart,
    float* __restrict__ M, int* __restrict__ partial,
    int* __restrict__ deg, float* __restrict__ dis) {
  int bid = blockIdx.x, tid = threadIdx.x;
  if (bid < 32) {
    int j = bid * 256 + tid;
    float s0 = 0.f, s1 = 0.f;
    #pragma unroll 4
    for (int k = 0; k < XB; ++k) {
      s0 += Mpart[(size_t)k * (DIM * DIM) + j];
      s1 += Mpart[(size_t)k * (DIM * DIM) + j + 8192];
    }
    M[j] = s0; M[j + 8192] = s1;
  } else {
    int bin = (bid - 32) * 256 + tid;
    int run = 0;
    #pragma unroll 4
    for (int b = 0; b < HB; ++b) {
      int v = partial[(size_t)b * NN + bin];
      partial[(size_t)b * NN + bin] = run;   // exclusive chunk prefix
      run += v;
    }
    int d = run + 1;                          // + self-loop
    deg[bin] = d;
    dis[bin] = rsqrtf((float)d);
  }
}

// ---------------- K4: offs = exclusive scan of edge counts (shfl, 2 barriers)
__global__ __launch_bounds__(1024) void k_scan(const int* __restrict__ deg,
    int* __restrict__ offs) {
  __shared__ int wsum[16];
  int t = threadIdx.x;
  int lane = t & 63, wave = t >> 6;
  int base_i = t * 8;
  int local[8], s = 0;
  int4 d0 = *(const int4*)(deg + base_i);
  int4 d1 = *(const int4*)(deg + base_i + 4);
  int cnt[8] = {d0.x - 1, d0.y - 1, d0.z - 1, d0.w - 1,
                d1.x - 1, d1.y - 1, d1.z - 1, d1.w - 1};
  #pragma unroll
  for (int j = 0; j < 8; ++j) { local[j] = s; s += cnt[j]; }
  int tot = s, sc = s;
  #pragma unroll
  for (int off = 1; off < 64; off <<= 1) {
    int v = __shfl_up(sc, off);
    if (lane >= off) sc += v;
  }
  if (lane == 63) wsum[wave] = sc;
  __syncthreads();
  if (wave == 0) {
    int v = (lane < 16) ? wsum[lane] : 0;
    #pragma unroll
    for (int off = 1; off < 16; off <<= 1) {
      int u = __shfl_up(v, off);
      if (lane >= off) v += u;
    }
    if (lane < 16) wsum[lane] = v;
  }
  __syncthreads();
  int base = (wave ? wsum[wave - 1] : 0) + sc - tot;
  #pragma unroll
  for (int j = 0; j < 8; ++j) offs[base_i + j] = base + local[j];
}

// ---------------- K5: atomic-free placement (standalone — do NOT fuse with
// the GEMM: r3 showed fusion forces the GEMM into 32 VGPRs and a 7x slowdown)
__global__ __launch_bounds__(256) void k_place(const int* __restrict__ ei,
    const int* __restrict__ offs, const int* __restrict__ partial,
    const int* __restrict__ rank, int* __restrict__ sorted) {
  int bid = blockIdx.x, tid = threadIdx.x;
  int e0 = bid * EPB + tid * EPT;
  int4 s0 = *(const int4*)(ei + e0);            // sources
  int4 s1 = *(const int4*)(ei + e0 + 4);
  int4 c0 = *(const int4*)(ei + NE + e0);       // targets
  int4 c1 = *(const int4*)(ei + NE + e0 + 4);
  int4 r0 = *(const int4*)(rank + e0);
  int4 r1 = *(const int4*)(rank + e0 + 4);
  const int* pfx = partial + (size_t)bid * NN;
  sorted[offs[c0.x] + pfx[c0.x] + r0.x] = s0.x;
  sorted[offs[c0.y] + pfx[c0.y] + r0.y] = s0.y;
  sorted[offs[c0.z] + pfx[c0.z] + r0.z] = s0.z;
  sorted[offs[c0.w] + pfx[c0.w] + r0.w] = s0.w;
  sorted[offs[c1.x] + pfx[c1.x] + r1.x] = s1.x;
  sorted[offs[c1.y] + pfx[c1.y] + r1.y] = s1.y;
  sorted[offs[c1.z] + pfx[c1.z] + r1.z] = s1.z;
  sorted[offs[c1.w] + pfx[c1.w] + r1.w] = s1.w;
}

// ---------------- K6: xws = (X@W)*dis and att = sigmoid(rinv*(X@M))
// verbatim round-2 structure: 512 blocks, x-tile in LDS, W/M streamed, no
// inner barriers, 16 independent accumulators.
__global__ __launch_bounds__(256) void k_xw_att(const float* __restrict__ x,
    const float* __restrict__ W, const float* __restrict__ M,
    const float* __restrict__ rinv, const float* __restrict__ dis,
    float* __restrict__ xws, float* __restrict__ att) {
  __shared__ float xs[RWB * DIM];   // 8 KB
  __shared__ float rvs[RWB], dss[RWB];
  int tid = threadIdx.x;
  int row0 = blockIdx.x * RWB;
  const float4* xsrc = (const float4*)(x + (size_t)row0 * DIM);
  float4* xdst = (float4*)xs;
  xdst[tid]       = xsrc[tid];
  xdst[tid + 256] = xsrc[tid + 256];
  if (tid < RWB) { rvs[tid] = rinv[row0 + tid]; dss[tid] = dis[row0 + tid]; }
  __syncthreads();

  int ty = tid >> 5, tx = tid & 31;
  int r0 = ty * 2, r1 = r0 + 1;
  float4 aw0 = {0,0,0,0}, aw1 = {0,0,0,0}, am0 = {0,0,0,0}, am1 = {0,0,0,0};
  const float* Wp = W + tx * 4;
  const float* Mp = M + tx * 4;

  #pragma unroll 4
  for (int k = 0; k < DIM; ++k) {
    float4 wv = *(const float4*)(Wp + k * DIM);
    float4 mv = *(const float4*)(Mp + k * DIM);
    float x0 = xs[r0 * DIM + k];
    float x1 = xs[r1 * DIM + k];
    aw0.x += x0 * wv.x; aw0.y += x0 * wv.y; aw0.z += x0 * wv.z; aw0.w += x0 * wv.w;
    aw1.x += x1 * wv.x; aw1.y += x1 * wv.y; aw1.z += x1 * wv.z; aw1.w += x1 * wv.w;
    am0.x += x0 * mv.x; am0.y += x0 * mv.y; am0.z += x0 * mv.z; am0.w += x0 * mv.w;
    am1.x += x1 * mv.x; am1.y += x1 * mv.y; am1.z += x1 * mv.z; am1.w += x1 * mv.w;
  }

  float rv0 = rvs[r0], rv1 = rvs[r1];
  float ds0 = dss[r0], ds1 = dss[r1];
  size_t o0 = (size_t)(row0 + r0) * DIM + tx * 4;
  size_t o1 = (size_t)(row0 + r1) * DIM + tx * 4;
  float4 w0 = {aw0.x * ds0, aw0.y * ds0, aw0.z * ds0, aw0.w * ds0};
  float4 w1 = {aw1.x * ds1, aw1.y * ds1, aw1.z * ds1, aw1.w * ds1};
  *(float4*)&xws[o0] = w0;
  *(float4*)&xws[o1] = w1;
  float4 g0, g1;
  g0.x = 1.0f / (1.0f + __expf(-am0.x * rv0));
  g0.y = 1.0f / (1.0f + __expf(-am0.y * rv0));
  g0.z = 1.0f / (1.0f + __expf(-am0.z * rv0));
  g0.w = 1.0f / (1.0f + __expf(-am0.w * rv0));
  g1.x = 1.0f / (1.0f + __expf(-am1.x * rv1));
  g1.y = 1.0f / (1.0f + __expf(-am1.y * rv1));
  g1.z = 1.0f / (1.0f + __expf(-am1.z * rv1));
  g1.w = 1.0f / (1.0f + __expf(-am1.w * rv1));
  *(float4*)&att[o0] = g0;
  *(float4*)&att[o1] = g1;
}

// ---------------- K7: CSR gather (pure row sums of xws) + epilogue
__global__ __launch_bounds__(128) void k_gather(const int* __restrict__ sorted,
    const int* __restrict__ offs, const int* __restrict__ deg,
    const float* __restrict__ dis, const float* __restrict__ xws,
    const float* __restrict__ att, const float* __restrict__ bias,
    float* __restrict__ out) {
  int c = blockIdx.x, t = threadIdx.x;
  int base = offs[c];
  int cnt  = deg[c] - 1;
  float acc = xws[(size_t)c * DIM + t];        // self-loop term
  int k = 0;
  for (; k + 4 <= cnt; k += 4) {
    int s0 = sorted[base + k + 0];
    int s1 = sorted[base + k + 1];
    int s2 = sorted[base + k + 2];
    int s3 = sorted[base + k + 3];
    acc += xws[(size_t)s0 * DIM + t];
    acc += xws[(size_t)s1 * DIM + t];
    acc += xws[(size_t)s2 * DIM + t];
    acc += xws[(size_t)s3 * DIM + t];
  }
  for (; k < cnt; ++k) acc += xws[(size_t)sorted[base + k] * DIM + t];
  float g = acc * dis[c] + bias[t];
  out[(size_t)c * DIM + t] = g * att[(size_t)c * DIM + t];
}

// ---------------------------------------------------------------------- launch
extern "C" void kernel_launch(void* const* d_in, const int* in_sizes, int n_in,
                              void* d_out, int out_size, void* d_ws, size_t ws_size,
                              hipStream_t stream) {
  const float* x  = (const float*)d_in[0];
  const int*   ei = (const int*)  d_in[1];
  const float* W  = (const float*)d_in[2];
  const float* b  = (const float*)d_in[3];
  float* out = (float*)d_out;

  // ws layout (~22 MB of the workspace)
  float* xws     = (float*)d_ws;                     // NN*DIM
  float* att     = xws + (size_t)NN * DIM;           // NN*DIM
  float* Mpart   = att + (size_t)NN * DIM;           // XB*DIM*DIM
  float* M       = Mpart + (size_t)XB * DIM * DIM;   // DIM*DIM
  float* rinv    = M + DIM * DIM;                    // NN
  float* dis     = rinv + NN;                        // NN
  int*   deg     = (int*)(dis + NN);                 // NN
  int*   offs    = deg + NN;                         // NN
  int*   rank    = offs + NN;                        // NE
  int*   partial = rank + NE;                        // HB*NN
  int*   sorted  = partial + (size_t)HB * NN;        // NE

  k_prep       <<<2048 + HB, 256, 0, stream>>>(x, ei, rinv, rank, partial);
  k_xtx_partial<<<XB, 256, 0, stream>>>(x, rinv, Mpart);
  k_mid        <<<64, 256, 0, stream>>>(Mpart, M, partial, deg, dis);
  k_scan       <<<1, 1024, 0, stream>>>(deg, offs);
  k_place      <<<HB, 256, 0, stream>>>(ei, offs, partial, rank, sorted);
  k_xw_att     <<<NN / RWB, 256, 0, stream>>>(x, W, M, rinv, dis, xws, att);
  k_gather     <<<NN, 128, 0, stream>>>(sorted, offs, deg, dis, xws, att, b, out);
}

// Round 5
// 129.244 us; speedup vs baseline: 1.4194x; 1.4194x over previous
//
#include <hip/hip_runtime.h>
#include <math.h>

#define NN  8192
#define DIM 128
#define NE  262144
#define XB  128          // xtx partial blocks (64 rows each)
#define HB  128          // histogram / placement chunks
#define EPB (NE / HB)    // 2048 edges per chunk
#define EPT (EPB / 256)  // 8 edges per thread
#define RWB 16           // rows per xw_att block
#define BK  16           // k-chunk rows of W/M staged in LDS per step

// ---------------- K1: row norms (blocks [0,2048)) + LDS-private histogram
// (blocks [2048,2048+HB)). Hist saves per-edge local rank -> placement needs
// NO atomics later. partial[h][bin] = per-chunk count.
__global__ __launch_bounds__(256) void k_prep(const float* __restrict__ x,
    const int* __restrict__ ei, float* __restrict__ rinv,
    int* __restrict__ rank, int* __restrict__ partial) {
  __shared__ int ldeg[NN];   // 32 KB
  int bid = blockIdx.x, tid = threadIdx.x;
  if (bid < 2048) {
    int wave = tid >> 6, lane = tid & 63;
    int row  = bid * 4 + wave;
    const float2* x2 = (const float2*)(x + (size_t)row * DIM);
    float2 v = x2[lane];
    float ss = v.x * v.x + v.y * v.y;
    #pragma unroll
    for (int m = 32; m; m >>= 1) ss += __shfl_xor(ss, m);
    if (lane == 0) rinv[row] = 1.0f / sqrtf(ss);
  } else {
    int h = bid - 2048;
    int4* lz = (int4*)ldeg;
    #pragma unroll
    for (int i = tid; i < NN / 4; i += 256) lz[i] = make_int4(0, 0, 0, 0);
    __syncthreads();
    int e0 = h * EPB + tid * EPT;
    int4 c0 = *(const int4*)(ei + NE + e0);      // targets
    int4 c1 = *(const int4*)(ei + NE + e0 + 4);
    int r0 = atomicAdd(&ldeg[c0.x], 1);
    int r1 = atomicAdd(&ldeg[c0.y], 1);
    int r2 = atomicAdd(&ldeg[c0.z], 1);
    int r3 = atomicAdd(&ldeg[c0.w], 1);
    int r4 = atomicAdd(&ldeg[c1.x], 1);
    int r5 = atomicAdd(&ldeg[c1.y], 1);
    int r6 = atomicAdd(&ldeg[c1.z], 1);
    int r7 = atomicAdd(&ldeg[c1.w], 1);
    *(int4*)(rank + e0)     = make_int4(r0, r1, r2, r3);
    *(int4*)(rank + e0 + 4) = make_int4(r4, r5, r6, r7);
    __syncthreads();
    #pragma unroll
    for (int i = tid * 4; i < NN; i += 1024)
      *(int4*)(partial + (size_t)h * NN + i) = *(int4*)&ldeg[i];
  }
}

// ---------------- K2: M = X^T X partials. 128 blocks x 64 rows, staged once.
__global__ __launch_bounds__(256) void k_xtx_partial(const float* __restrict__ x,
    const float* __restrict__ rinv, float* __restrict__ Mpart) {
  __shared__ float xs[64 * DIM];   // 32 KB
  __shared__ float rvs[64];
  int tid = threadIdx.x;
  int row0 = blockIdx.x * 64;
  const float4* xsrc = (const float4*)(x + (size_t)row0 * DIM);
  float4* xdst = (float4*)xs;
  #pragma unroll
  for (int i = 0; i < 8; ++i) xdst[tid + 256 * i] = xsrc[tid + 256 * i];
  if (tid < 64) rvs[tid] = rinv[row0 + tid];
  __syncthreads();

  int ty = tid >> 4, tx = tid & 15;
  float acc[8][8];
  #pragma unroll
  for (int i = 0; i < 8; ++i)
    #pragma unroll
    for (int j = 0; j < 8; ++j) acc[i][j] = 0.f;

  #pragma unroll 2
  for (int r = 0; r < 64; ++r) {
    float4 a0 = *(const float4*)&xs[r * DIM + ty * 8];
    float4 a1 = *(const float4*)&xs[r * DIM + ty * 8 + 4];
    float4 b0 = *(const float4*)&xs[r * DIM + tx * 8];
    float4 b1 = *(const float4*)&xs[r * DIM + tx * 8 + 4];
    float rv = rvs[r];
    float a[8] = {a0.x * rv, a0.y * rv, a0.z * rv, a0.w * rv,
                  a1.x * rv, a1.y * rv, a1.z * rv, a1.w * rv};
    float b[8] = {b0.x, b0.y, b0.z, b0.w, b1.x, b1.y, b1.z, b1.w};
    #pragma unroll
    for (int i = 0; i < 8; ++i)
      #pragma unroll
      for (int j = 0; j < 8; ++j) acc[i][j] += a[i] * b[j];
  }
  float* o = Mpart + (size_t)blockIdx.x * (DIM * DIM);
  #pragma unroll
  for (int i = 0; i < 8; ++i) {
    *(float4*)&o[(ty * 8 + i) * DIM + tx * 8]     = make_float4(acc[i][0], acc[i][1], acc[i][2], acc[i][3]);
    *(float4*)&o[(ty * 8 + i) * DIM + tx * 8 + 4] = make_float4(acc[i][4], acc[i][5], acc[i][6], acc[i][7]);
  }
}

// ---------------- K3: fused Mpart reduce (blocks [0,32)) + per-bin column
// scan of partial (blocks [32,64)) -> chunk prefixes in place, deg, dis.
__global__ __launch_bounds__(256) void k_mid(const float* __restrict__ Mpart,
    float* __restrict__ M, int* __restrict__ partial,
    int* __restrict__ deg, float* __restrict__ dis) {
  int bid = blockIdx.x, tid = threadIdx.x;
  if (bid < 32) {
    int j = bid * 256 + tid;
    float s0 = 0.f, s1 = 0.f;
    #pragma unroll 4
    for (int k = 0; k < XB; ++k) {
      s0 += Mpart[(size_t)k * (DIM * DIM) + j];
      s1 += Mpart[(size_t)k * (DIM * DIM) + j + 8192];
    }
    M[j] = s0; M[j + 8192] = s1;
  } else {
    int bin = (bid - 32) * 256 + tid;
    int run = 0;
    #pragma unroll 4
    for (int b = 0; b < HB; ++b) {
      int v = partial[(size_t)b * NN + bin];
      partial[(size_t)b * NN + bin] = run;   // exclusive chunk prefix
      run += v;
    }
    int d = run + 1;                          // + self-loop
    deg[bin] = d;
    dis[bin] = rsqrtf((float)d);
  }
}

// ---------------- K4: offs = exclusive scan of edge counts (shfl, 2 barriers)
__global__ __launch_bounds__(1024) void k_scan(const int* __restrict__ deg,
    int* __restrict__ offs) {
  __shared__ int wsum[16];
  int t = threadIdx.x;
  int lane = t & 63, wave = t >> 6;
  int base_i = t * 8;
  int local[8], s = 0;
  int4 d0 = *(const int4*)(deg + base_i);
  int4 d1 = *(const int4*)(deg + base_i + 4);
  int cnt[8] = {d0.x - 1, d0.y - 1, d0.z - 1, d0.w - 1,
                d1.x - 1, d1.y - 1, d1.z - 1, d1.w - 1};
  #pragma unroll
  for (int j = 0; j < 8; ++j) { local[j] = s; s += cnt[j]; }
  int tot = s, sc = s;
  #pragma unroll
  for (int off = 1; off < 64; off <<= 1) {
    int v = __shfl_up(sc, off);
    if (lane >= off) sc += v;
  }
  if (lane == 63) wsum[wave] = sc;
  __syncthreads();
  if (wave == 0) {
    int v = (lane < 16) ? wsum[lane] : 0;
    #pragma unroll
    for (int off = 1; off < 16; off <<= 1) {
      int u = __shfl_up(v, off);
      if (lane >= off) v += u;
    }
    if (lane < 16) wsum[lane] = v;
  }
  __syncthreads();
  int base = (wave ? wsum[wave - 1] : 0) + sc - tot;
  #pragma unroll
  for (int j = 0; j < 8; ++j) offs[base_i + j] = base + local[j];
}

// ---------------- K5: atomic-free placement (standalone)
__global__ __launch_bounds__(256) void k_place(const int* __restrict__ ei,
    const int* __restrict__ offs, const int* __restrict__ partial,
    const int* __restrict__ rank, int* __restrict__ sorted) {
  int bid = blockIdx.x, tid = threadIdx.x;
  int e0 = bid * EPB + tid * EPT;
  int4 s0 = *(const int4*)(ei + e0);            // sources
  int4 s1 = *(const int4*)(ei + e0 + 4);
  int4 c0 = *(const int4*)(ei + NE + e0);       // targets
  int4 c1 = *(const int4*)(ei + NE + e0 + 4);
  int4 r0 = *(const int4*)(rank + e0);
  int4 r1 = *(const int4*)(rank + e0 + 4);
  const int* pfx = partial + (size_t)bid * NN;
  sorted[offs[c0.x] + pfx[c0.x] + r0.x] = s0.x;
  sorted[offs[c0.y] + pfx[c0.y] + r0.y] = s0.y;
  sorted[offs[c0.z] + pfx[c0.z] + r0.z] = s0.z;
  sorted[offs[c0.w] + pfx[c0.w] + r0.w] = s0.w;
  sorted[offs[c1.x] + pfx[c1.x] + r1.x] = s1.x;
  sorted[offs[c1.y] + pfx[c1.y] + r1.y] = s1.y;
  sorted[offs[c1.z] + pfx[c1.z] + r1.z] = s1.z;
  sorted[offs[c1.w] + pfx[c1.w] + r1.w] = s1.w;
}

// ---------------- K6: xws = (X@W)*dis and att = sigmoid(rinv*(X@M))
// r4 showed streaming W/M from global in the K-loop is latency-catastrophic
// (compiler picked a 24-VGPR serial schedule; 512 blocks contend on the same
// L2 lines -> 77 us, VALUBusy 5.5%). Stage W/M in BK=16-row LDS chunks with
// bulk coalesced loads + barrier; inner loop is LDS-only with 16 independent
// accumulators. LDS = 8(x) + 8(W) + 8(M) KB.
__global__ __launch_bounds__(256) void k_xw_att(const float* __restrict__ x,
    const float* __restrict__ W, const float* __restrict__ M,
    const float* __restrict__ rinv, const float* __restrict__ dis,
    float* __restrict__ xws, float* __restrict__ att) {
  __shared__ float xs[RWB * DIM];   // 8 KB
  __shared__ float Wl[BK * DIM];    // 8 KB
  __shared__ float Ml[BK * DIM];    // 8 KB
  __shared__ float rvs[RWB], dss[RWB];
  int tid = threadIdx.x;
  int row0 = blockIdx.x * RWB;
  const float4* xsrc = (const float4*)(x + (size_t)row0 * DIM);
  float4* xdst = (float4*)xs;
  xdst[tid]       = xsrc[tid];
  xdst[tid + 256] = xsrc[tid + 256];
  if (tid < RWB) { rvs[tid] = rinv[row0 + tid]; dss[tid] = dis[row0 + tid]; }

  int ty = tid >> 5, tx = tid & 31;
  int r0 = ty * 2, r1 = r0 + 1;
  float4 aw0 = {0,0,0,0}, aw1 = {0,0,0,0}, am0 = {0,0,0,0}, am1 = {0,0,0,0};

  for (int kk = 0; kk < DIM; kk += BK) {
    __syncthreads();                       // protects Wl/Ml reuse (and covers xs on 1st pass)
    const float4* Ws = (const float4*)(W + (size_t)kk * DIM);
    const float4* Ms = (const float4*)(M + (size_t)kk * DIM);
    float4 w0s = Ws[tid], w1s = Ws[tid + 256];
    float4 m0s = Ms[tid], m1s = Ms[tid + 256];
    ((float4*)Wl)[tid]       = w0s;
    ((float4*)Wl)[tid + 256] = w1s;
    ((float4*)Ml)[tid]       = m0s;
    ((float4*)Ml)[tid + 256] = m1s;
    __syncthreads();
    #pragma unroll
    for (int k = 0; k < BK; ++k) {
      float4 wv = *(const float4*)&Wl[k * DIM + tx * 4];
      float4 mv = *(const float4*)&Ml[k * DIM + tx * 4];
      float x0 = xs[r0 * DIM + kk + k];
      float x1 = xs[r1 * DIM + kk + k];
      aw0.x += x0 * wv.x; aw0.y += x0 * wv.y; aw0.z += x0 * wv.z; aw0.w += x0 * wv.w;
      aw1.x += x1 * wv.x; aw1.y += x1 * wv.y; aw1.z += x1 * wv.z; aw1.w += x1 * wv.w;
      am0.x += x0 * mv.x; am0.y += x0 * mv.y; am0.z += x0 * mv.z; am0.w += x0 * mv.w;
      am1.x += x1 * mv.x; am1.y += x1 * mv.y; am1.z += x1 * mv.z; am1.w += x1 * mv.w;
    }
  }

  float rv0 = rvs[r0], rv1 = rvs[r1];
  float ds0 = dss[r0], ds1 = dss[r1];
  size_t o0 = (size_t)(row0 + r0) * DIM + tx * 4;
  size_t o1 = (size_t)(row0 + r1) * DIM + tx * 4;
  float4 w0 = {aw0.x * ds0, aw0.y * ds0, aw0.z * ds0, aw0.w * ds0};
  float4 w1 = {aw1.x * ds1, aw1.y * ds1, aw1.z * ds1, aw1.w * ds1};
  *(float4*)&xws[o0] = w0;
  *(float4*)&xws[o1] = w1;
  float4 g0, g1;
  g0.x = 1.0f / (1.0f + __expf(-am0.x * rv0));
  g0.y = 1.0f / (1.0f + __expf(-am0.y * rv0));
  g0.z = 1.0f / (1.0f + __expf(-am0.z * rv0));
  g0.w = 1.0f / (1.0f + __expf(-am0.w * rv0));
  g1.x = 1.0f / (1.0f + __expf(-am1.x * rv1));
  g1.y = 1.0f / (1.0f + __expf(-am1.y * rv1));
  g1.z = 1.0f / (1.0f + __expf(-am1.z * rv1));
  g1.w = 1.0f / (1.0f + __expf(-am1.w * rv1));
  *(float4*)&att[o0] = g0;
  *(float4*)&att[o1] = g1;
}

// ---------------- K7: CSR gather (pure row sums of xws) + epilogue
__global__ __launch_bounds__(128) void k_gather(const int* __restrict__ sorted,
    const int* __restrict__ offs, const int* __restrict__ deg,
    const float* __restrict__ dis, const float* __restrict__ xws,
    const float* __restrict__ att, const float* __restrict__ bias,
    float* __restrict__ out) {
  int c = blockIdx.x, t = threadIdx.x;
  int base = offs[c];
  int cnt  = deg[c] - 1;
  float acc = xws[(size_t)c * DIM + t];        // self-loop term
  int k = 0;
  for (; k + 4 <= cnt; k += 4) {
    int s0 = sorted[base + k + 0];
    int s1 = sorted[base + k + 1];
    int s2 = sorted[base + k + 2];
    int s3 = sorted[base + k + 3];
    acc += xws[(size_t)s0 * DIM + t];
    acc += xws[(size_t)s1 * DIM + t];
    acc += xws[(size_t)s2 * DIM + t];
    acc += xws[(size_t)s3 * DIM + t];
  }
  for (; k < cnt; ++k) acc += xws[(size_t)sorted[base + k] * DIM + t];
  float g = acc * dis[c] + bias[t];
  out[(size_t)c * DIM + t] = g * att[(size_t)c * DIM + t];
}

// ---------------------------------------------------------------------- launch
extern "C" void kernel_launch(void* const* d_in, const int* in_sizes, int n_in,
                              void* d_out, int out_size, void* d_ws, size_t ws_size,
                              hipStream_t stream) {
  const float* x  = (const float*)d_in[0];
  const int*   ei = (const int*)  d_in[1];
  const float* W  = (const float*)d_in[2];
  const float* b  = (const float*)d_in[3];
  float* out = (float*)d_out;

  // ws layout (~22 MB of the workspace)
  float* xws     = (float*)d_ws;                     // NN*DIM
  float* att     = xws + (size_t)NN * DIM;           // NN*DIM
  float* Mpart   = att + (size_t)NN * DIM;           // XB*DIM*DIM
  float* M       = Mpart + (size_t)XB * DIM * DIM;   // DIM*DIM
  float* rinv    = M + DIM * DIM;                    // NN
  float* dis     = rinv + NN;                        // NN
  int*   deg     = (int*)(dis + NN);                 // NN
  int*   offs    = deg + NN;                         // NN
  int*   rank    = offs + NN;                        // NE
  int*   partial = rank + NE;                        // HB*NN
  int*   sorted  = partial + (size_t)HB * NN;        // NE

  k_prep       <<<2048 + HB, 256, 0, stream>>>(x, ei, rinv, rank, partial);
  k_xtx_partial<<<XB, 256, 0, stream>>>(x, rinv, Mpart);
  k_mid        <<<64, 256, 0, stream>>>(Mpart, M, partial, deg, dis);
  k_scan       <<<1, 1024, 0, stream>>>(deg, offs);
  k_place      <<<HB, 256, 0, stream>>>(ei, offs, partial, rank, sorted);
  k_xw_att     <<<NN / RWB, 256, 0, stream>>>(x, W, M, rinv, dis, xws, att);
  k_gather     <<<NN, 128, 0, stream>>>(sorted, offs, deg, dis, xws, att, b, out);
}

// Round 7
// 119.747 us; speedup vs baseline: 1.5320x; 1.0793x over previous
//
#include <hip/hip_runtime.h>
#include <math.h>

#define NN  8192
#define DIM 128
#define NE  262144
#define XB  128          // xtx partial blocks (64 rows each)
#define HB  128          // histogram / placement chunks
#define EPB (NE / HB)    // 2048 edges per chunk
#define EPT (EPB / 256)  // 8 edges per thread
#define RWB 32           // rows per xw_att block (4 per thread)
#define BK  16           // k-chunk rows of W/M staged in LDS per step

// bf16 via explicit bit math (this ROCm's __hip_bfloat16 lacks .data)
static __device__ __forceinline__ unsigned short f2bf(float f) {
  unsigned int u = __float_as_uint(f);
  return (unsigned short)((u + 0x7FFFu + ((u >> 16) & 1u)) >> 16);   // RNE
}
static __device__ __forceinline__ float bf2f(unsigned short h) {
  return __uint_as_float((unsigned int)h << 16);
}

// ---------------- K1: fused xtx-partials (blocks [0,128)) + row norms
// (blocks [128,2176)) + LDS-private histogram (blocks [2176,2304)).
__global__ __launch_bounds__(256) void k_prep(const float* __restrict__ x,
    const int* __restrict__ ei, float* __restrict__ rinv,
    int* __restrict__ rank, int* __restrict__ partial,
    float* __restrict__ Mpart) {
  __shared__ float smem[64 * DIM + 64];   // 32.25 KB (xtx: xs+rvs; hist: ldeg)
  int bid = blockIdx.x, tid = threadIdx.x;
  if (bid < XB) {
    // ---- xtx partial: 64 rows staged once, barrier-free outer products
    float* xs  = smem;
    float* rvs = smem + 64 * DIM;
    int row0 = bid * 64;
    const float4* xsrc = (const float4*)(x + (size_t)row0 * DIM);
    float4* xdst = (float4*)xs;
    #pragma unroll
    for (int i = 0; i < 8; ++i) xdst[tid + 256 * i] = xsrc[tid + 256 * i];
    __syncthreads();
    // local row norms: 4 lanes per row
    int rr = tid >> 2, q = tid & 3;
    const float4* xr = (const float4*)&xs[rr * DIM + q * 32];
    float ss = 0.f;
    #pragma unroll
    for (int i = 0; i < 8; ++i) {
      float4 v = xr[i];
      ss += v.x * v.x + v.y * v.y + v.z * v.z + v.w * v.w;
    }
    ss += __shfl_xor(ss, 1);
    ss += __shfl_xor(ss, 2);
    if (q == 0) rvs[rr] = 1.0f / sqrtf(ss);
    __syncthreads();

    int ty = tid >> 4, tx = tid & 15;
    float acc[8][8];
    #pragma unroll
    for (int i = 0; i < 8; ++i)
      #pragma unroll
      for (int j = 0; j < 8; ++j) acc[i][j] = 0.f;

    #pragma unroll 2
    for (int r = 0; r < 64; ++r) {
      float4 a0 = *(const float4*)&xs[r * DIM + ty * 8];
      float4 a1 = *(const float4*)&xs[r * DIM + ty * 8 + 4];
      float4 b0 = *(const float4*)&xs[r * DIM + tx * 8];
      float4 b1 = *(const float4*)&xs[r * DIM + tx * 8 + 4];
      float rv = rvs[r];
      float a[8] = {a0.x * rv, a0.y * rv, a0.z * rv, a0.w * rv,
                    a1.x * rv, a1.y * rv, a1.z * rv, a1.w * rv};
      float b[8] = {b0.x, b0.y, b0.z, b0.w, b1.x, b1.y, b1.z, b1.w};
      #pragma unroll
      for (int i = 0; i < 8; ++i)
        #pragma unroll
        for (int j = 0; j < 8; ++j) acc[i][j] += a[i] * b[j];
    }
    float* o = Mpart + (size_t)bid * (DIM * DIM);
    #pragma unroll
    for (int i = 0; i < 8; ++i) {
      *(float4*)&o[(ty * 8 + i) * DIM + tx * 8]     = make_float4(acc[i][0], acc[i][1], acc[i][2], acc[i][3]);
      *(float4*)&o[(ty * 8 + i) * DIM + tx * 8 + 4] = make_float4(acc[i][4], acc[i][5], acc[i][6], acc[i][7]);
    }
  } else if (bid < XB + 2048) {
    // ---- row norms -> global rinv (consumed only by later kernels)
    int wave = tid >> 6, lane = tid & 63;
    int row  = (bid - XB) * 4 + wave;
    const float2* x2 = (const float2*)(x + (size_t)row * DIM);
    float2 v = x2[lane];
    float ss = v.x * v.x + v.y * v.y;
    #pragma unroll
    for (int m = 32; m; m >>= 1) ss += __shfl_xor(ss, m);
    if (lane == 0) rinv[row] = 1.0f / sqrtf(ss);
  } else {
    // ---- LDS-private histogram; saves per-edge local rank
    int h = bid - (XB + 2048);
    int* ldeg = (int*)smem;
    int4* lz = (int4*)ldeg;
    #pragma unroll
    for (int i = tid; i < NN / 4; i += 256) lz[i] = make_int4(0, 0, 0, 0);
    __syncthreads();
    int e0 = h * EPB + tid * EPT;
    int4 c0 = *(const int4*)(ei + NE + e0);      // targets
    int4 c1 = *(const int4*)(ei + NE + e0 + 4);
    int r0 = atomicAdd(&ldeg[c0.x], 1);
    int r1 = atomicAdd(&ldeg[c0.y], 1);
    int r2 = atomicAdd(&ldeg[c0.z], 1);
    int r3 = atomicAdd(&ldeg[c0.w], 1);
    int r4 = atomicAdd(&ldeg[c1.x], 1);
    int r5 = atomicAdd(&ldeg[c1.y], 1);
    int r6 = atomicAdd(&ldeg[c1.z], 1);
    int r7 = atomicAdd(&ldeg[c1.w], 1);
    *(int4*)(rank + e0)     = make_int4(r0, r1, r2, r3);
    *(int4*)(rank + e0 + 4) = make_int4(r4, r5, r6, r7);
    __syncthreads();
    #pragma unroll
    for (int i = tid * 4; i < NN; i += 1024)
      *(int4*)(partial + (size_t)h * NN + i) = *(int4*)&ldeg[i];
  }
}

// ---------------- K2: Mpart reduce (blocks [0,64)) + int4 column scan of
// partial (blocks [64,72)) -> chunk prefixes in place, deg, dis.
__global__ __launch_bounds__(256) void k_mid(const float* __restrict__ Mpart,
    float* __restrict__ M, int* __restrict__ partial,
    int* __restrict__ deg, float* __restrict__ dis) {
  int bid = blockIdx.x, tid = threadIdx.x;
  if (bid < 64) {
    int j = bid * 256 + tid;
    float s = 0.f;
    #pragma unroll 4
    for (int k = 0; k < XB; ++k) s += Mpart[(size_t)k * (DIM * DIM) + j];
    M[j] = s;
  } else {
    int idx = (bid - 64) * 256 + tid;          // 2048 threads x 4 bins
    int4 run = make_int4(0, 0, 0, 0);
    #pragma unroll 4
    for (int b = 0; b < HB; ++b) {
      int4* p4 = (int4*)(partial + (size_t)b * NN);
      int4 v = p4[idx];
      p4[idx] = run;                            // exclusive chunk prefix
      run.x += v.x; run.y += v.y; run.z += v.z; run.w += v.w;
    }
    int4 d = make_int4(run.x + 1, run.y + 1, run.z + 1, run.w + 1);
    *(int4*)(deg + idx * 4) = d;
    float4 ds;
    ds.x = rsqrtf((float)d.x); ds.y = rsqrtf((float)d.y);
    ds.z = rsqrtf((float)d.z); ds.w = rsqrtf((float)d.w);
    *(float4*)(dis + idx * 4) = ds;
  }
}

// ---------------- K3: offs = exclusive scan of edge counts (shfl, 2 barriers)
__global__ __launch_bounds__(1024) void k_scan(const int* __restrict__ deg,
    int* __restrict__ offs) {
  __shared__ int wsum[16];
  int t = threadIdx.x;
  int lane = t & 63, wave = t >> 6;
  int base_i = t * 8;
  int local[8], s = 0;
  int4 d0 = *(const int4*)(deg + base_i);
  int4 d1 = *(const int4*)(deg + base_i + 4);
  int cnt[8] = {d0.x - 1, d0.y - 1, d0.z - 1, d0.w - 1,
                d1.x - 1, d1.y - 1, d1.z - 1, d1.w - 1};
  #pragma unroll
  for (int j = 0; j < 8; ++j) { local[j] = s; s += cnt[j]; }
  int tot = s, sc = s;
  #pragma unroll
  for (int off = 1; off < 64; off <<= 1) {
    int v = __shfl_up(sc, off);
    if (lane >= off) sc += v;
  }
  if (lane == 63) wsum[wave] = sc;
  __syncthreads();
  if (wave == 0) {
    int v = (lane < 16) ? wsum[lane] : 0;
    #pragma unroll
    for (int off = 1; off < 16; off <<= 1) {
      int u = __shfl_up(v, off);
      if (lane >= off) v += u;
    }
    if (lane < 16) wsum[lane] = v;
  }
  __syncthreads();
  int base = (wave ? wsum[wave - 1] : 0) + sc - tot;
  #pragma unroll
  for (int j = 0; j < 8; ++j) offs[base_i + j] = base + local[j];
}

// ---------------- K4: xws(bf16) = (X@W)*dis and att = sigmoid(rinv*(X@M))
// (blocks [0,256), 4 rows x 4+4 cols per thread, W/M in BK-row LDS chunks)
// + atomic-free placement (blocks [256,384)).
__global__ __launch_bounds__(256) void k_main(const float* __restrict__ x,
    const float* __restrict__ W, const float* __restrict__ M,
    const float* __restrict__ rinv, const float* __restrict__ dis,
    const int* __restrict__ ei, const int* __restrict__ offs,
    const int* __restrict__ partial, const int* __restrict__ rank,
    int* __restrict__ sorted, unsigned short* __restrict__ xws,
    float* __restrict__ att) {
  __shared__ float xs[RWB * DIM];   // 16 KB
  __shared__ float Wl[BK * DIM];    // 8 KB
  __shared__ float Ml[BK * DIM];    // 8 KB
  __shared__ float rvs[RWB], dss[RWB];
  int bid = blockIdx.x, tid = threadIdx.x;
  if (bid < NN / RWB) {
    int row0 = bid * RWB;
    const float4* xsrc = (const float4*)(x + (size_t)row0 * DIM);
    float4* xdst = (float4*)xs;
    #pragma unroll
    for (int i = 0; i < 4; ++i) xdst[tid + 256 * i] = xsrc[tid + 256 * i];
    if (tid < RWB) { rvs[tid] = rinv[row0 + tid]; dss[tid] = dis[row0 + tid]; }

    int ty = tid >> 5, tx = tid & 31;
    int r0 = ty * 4;
    float4 aw[4], am[4];
    #pragma unroll
    for (int j = 0; j < 4; ++j) { aw[j] = make_float4(0,0,0,0); am[j] = make_float4(0,0,0,0); }

    for (int kk = 0; kk < DIM; kk += BK) {
      __syncthreads();
      const float4* Ws = (const float4*)(W + (size_t)kk * DIM);
      const float4* Ms = (const float4*)(M + (size_t)kk * DIM);
      float4 w0s = Ws[tid], w1s = Ws[tid + 256];
      float4 m0s = Ms[tid], m1s = Ms[tid + 256];
      ((float4*)Wl)[tid]       = w0s;
      ((float4*)Wl)[tid + 256] = w1s;
      ((float4*)Ml)[tid]       = m0s;
      ((float4*)Ml)[tid + 256] = m1s;
      __syncthreads();
      #pragma unroll
      for (int k4 = 0; k4 < BK; k4 += 4) {
        float4 xf[4];
        #pragma unroll
        for (int j = 0; j < 4; ++j)
          xf[j] = *(const float4*)&xs[(r0 + j) * DIM + kk + k4];
        #pragma unroll
        for (int k = 0; k < 4; ++k) {
          float4 wv = *(const float4*)&Wl[(k4 + k) * DIM + tx * 4];
          float4 mv = *(const float4*)&Ml[(k4 + k) * DIM + tx * 4];
          #pragma unroll
          for (int j = 0; j < 4; ++j) {
            float xv = ((const float*)&xf[j])[k];
            aw[j].x += xv * wv.x; aw[j].y += xv * wv.y;
            aw[j].z += xv * wv.z; aw[j].w += xv * wv.w;
            am[j].x += xv * mv.x; am[j].y += xv * mv.y;
            am[j].z += xv * mv.z; am[j].w += xv * mv.w;
          }
        }
      }
    }

    #pragma unroll
    for (int j = 0; j < 4; ++j) {
      int row = row0 + r0 + j;
      float rv = rvs[r0 + j], ds = dss[r0 + j];
      size_t o = (size_t)row * DIM + tx * 4;
      ushort4 wb;
      wb.x = f2bf(aw[j].x * ds);
      wb.y = f2bf(aw[j].y * ds);
      wb.z = f2bf(aw[j].z * ds);
      wb.w = f2bf(aw[j].w * ds);
      *(ushort4*)&xws[o] = wb;
      float4 g;
      g.x = 1.0f / (1.0f + __expf(-am[j].x * rv));
      g.y = 1.0f / (1.0f + __expf(-am[j].y * rv));
      g.z = 1.0f / (1.0f + __expf(-am[j].z * rv));
      g.w = 1.0f / (1.0f + __expf(-am[j].w * rv));
      *(float4*)&att[o] = g;
    }
  } else {
    int pb = bid - NN / RWB;
    int e0 = pb * EPB + tid * EPT;
    int4 s0 = *(const int4*)(ei + e0);            // sources
    int4 s1 = *(const int4*)(ei + e0 + 4);
    int4 c0 = *(const int4*)(ei + NE + e0);       // targets
    int4 c1 = *(const int4*)(ei + NE + e0 + 4);
    int4 r0 = *(const int4*)(rank + e0);
    int4 r1 = *(const int4*)(rank + e0 + 4);
    const int* pfx = partial + (size_t)pb * NN;
    sorted[offs[c0.x] + pfx[c0.x] + r0.x] = s0.x;
    sorted[offs[c0.y] + pfx[c0.y] + r0.y] = s0.y;
    sorted[offs[c0.z] + pfx[c0.z] + r0.z] = s0.z;
    sorted[offs[c0.w] + pfx[c0.w] + r0.w] = s0.w;
    sorted[offs[c1.x] + pfx[c1.x] + r1.x] = s1.x;
    sorted[offs[c1.y] + pfx[c1.y] + r1.y] = s1.y;
    sorted[offs[c1.z] + pfx[c1.z] + r1.z] = s1.z;
    sorted[offs[c1.w] + pfx[c1.w] + r1.w] = s1.w;
  }
}

// ---------------- K5: CSR gather (bf16 row sums) + epilogue
__global__ __launch_bounds__(128) void k_gather(const int* __restrict__ sorted,
    const int* __restrict__ offs, const int* __restrict__ deg,
    const float* __restrict__ dis, const unsigned short* __restrict__ xws,
    const float* __restrict__ att, const float* __restrict__ bias,
    float* __restrict__ out) {
  int c = blockIdx.x, t = threadIdx.x;
  int base = offs[c];
  int cnt  = deg[c] - 1;
  float acc = bf2f(xws[(size_t)c * DIM + t]);   // self-loop term
  int k = 0;
  for (; k + 4 <= cnt; k += 4) {
    int s0 = sorted[base + k + 0];
    int s1 = sorted[base + k + 1];
    int s2 = sorted[base + k + 2];
    int s3 = sorted[base + k + 3];
    float v0 = bf2f(xws[(size_t)s0 * DIM + t]);
    float v1 = bf2f(xws[(size_t)s1 * DIM + t]);
    float v2 = bf2f(xws[(size_t)s2 * DIM + t]);
    float v3 = bf2f(xws[(size_t)s3 * DIM + t]);
    acc += v0 + v1 + v2 + v3;
  }
  for (; k < cnt; ++k)
    acc += bf2f(xws[(size_t)sorted[base + k] * DIM + t]);
  float g = acc * dis[c] + bias[t];
  out[(size_t)c * DIM + t] = g * att[(size_t)c * DIM + t];
}

// ---------------------------------------------------------------------- launch
extern "C" void kernel_launch(void* const* d_in, const int* in_sizes, int n_in,
                              void* d_out, int out_size, void* d_ws, size_t ws_size,
                              hipStream_t stream) {
  const float* x  = (const float*)d_in[0];
  const int*   ei = (const int*)  d_in[1];
  const float* W  = (const float*)d_in[2];
  const float* b  = (const float*)d_in[3];
  float* out = (float*)d_out;

  // ws layout (~20 MB)
  unsigned short* xws = (unsigned short*)d_ws;        // NN*DIM bf16 (2 MB)
  float* att     = (float*)(xws + (size_t)NN * DIM);  // NN*DIM
  float* Mpart   = att + (size_t)NN * DIM;            // XB*DIM*DIM
  float* M       = Mpart + (size_t)XB * DIM * DIM;    // DIM*DIM
  float* rinv    = M + DIM * DIM;                     // NN
  float* dis     = rinv + NN;                         // NN
  int*   deg     = (int*)(dis + NN);                  // NN
  int*   offs    = deg + NN;                          // NN
  int*   rank    = offs + NN;                         // NE
  int*   partial = rank + NE;                         // HB*NN
  int*   sorted  = partial + (size_t)HB * NN;         // NE

  k_prep   <<<XB + 2048 + HB, 256, 0, stream>>>(x, ei, rinv, rank, partial, Mpart);
  k_mid    <<<72, 256, 0, stream>>>(Mpart, M, partial, deg, dis);
  k_scan   <<<1, 1024, 0, stream>>>(deg, offs);
  k_main   <<<NN / RWB + HB, 256, 0, stream>>>(x, W, M, rinv, dis, ei, offs,
                                               partial, rank, sorted, xws, att);
  k_gather <<<NN, 128, 0, stream>>>(sorted, offs, deg, dis, xws, att, b, out);
}